// Round 1
// 694.138 us; speedup vs baseline: 1.0203x; 1.0203x over previous
//
#include <hip/hip_runtime.h>
#include <math.h>

// Problem dims
constexpr int kH  = 1024;
constexpr int kV  = 50257;
constexpr int kS  = 4096;
constexpr int kH4 = kH / 4;    // 256 float4 per H row
constexpr int kH2 = 2 * kH;    // 2048

// Workspace layout (float offsets) — all 16B-aligned
constexpr int WS_H0     = 0;       // 1024
constexpr int WS_GH1    = 1024;    // 3072
constexpr int WS_H1     = 4096;    // 1024
constexpr int WS_V      = 5120;    // 1024
constexpr int WS_CTX    = 6144;    // 1024
constexpr int WS_ATTN   = 7168;    // 4096
constexpr int WS_E      = 11264;   // 4096
constexpr int WS_SC     = 15360;   // [0]=c  [1]=max  [2]=lse
constexpr int WS_LOGITS = 15424;   // 50257
// total ~65681 floats ~ 257 KB

// d_out layout (floats): logits | context | hidden(h0,h1) | attn
constexpr int OUT_LOGITS = 0;
constexpr int OUT_CTX    = kV;                 // 50257 (NOT 16B aligned -> scalar stores only)
constexpr int OUT_HID    = kV + kH;            // 51281
constexpr int OUT_ATTN   = kV + kH + 2 * kH;   // 53329

__device__ __forceinline__ float wred_sum(float v) {
#pragma unroll
  for (int o = 32; o > 0; o >>= 1) v += __shfl_down(v, o, 64);
  return v;  // valid in lane 0
}
__device__ __forceinline__ float wred_max(float v) {
#pragma unroll
  for (int o = 32; o > 0; o >>= 1) v = fmaxf(v, __shfl_down(v, o, 64));
  return v;  // valid in lane 0
}
__device__ __forceinline__ float sigmoidf_(float x) { return 1.0f / (1.0f + __expf(-x)); }
__device__ __forceinline__ float dot4(float4 a, float4 b) {
  return a.x * b.x + a.y * b.y + a.z * b.z + a.w * b.w;
}

// Non-temporal float4 load (single-use weight streams: don't pollute L2/L3)
typedef float f32x4_t __attribute__((ext_vector_type(4)));
__device__ __forceinline__ float4 ntld(const float4* p) {
  f32x4_t v = __builtin_nontemporal_load((const f32x4_t*)p);
  return make_float4(v.x, v.y, v.z, v.w);
}

// K1: blocks [0,256): GRU0 -> h0 ; blocks [256,1024): gh1 = W_hh1 @ h_prev1 + b_hh1
__global__ void k1_gru0_gh1(const int* __restrict__ wi_p, const float* __restrict__ lc,
                            const float* __restrict__ lh, const float* __restrict__ emb,
                            const float* __restrict__ W_ih0, const float* __restrict__ W_hh0,
                            const float* __restrict__ b_ih0, const float* __restrict__ b_hh0,
                            const float* __restrict__ W_hh1, const float* __restrict__ b_hh1,
                            float* __restrict__ ws) {
  const int wave = threadIdx.x >> 6, lane = threadIdx.x & 63;
  const int b = blockIdx.x;
  if (b < 256) {
    const int j = b * 4 + wave;
    const int wi = wi_p[0];
    const float4* embr = (const float4*)(emb + (size_t)wi * kH);
    const float4* lc4  = (const float4*)lc;
    const float4* Wr = (const float4*)(W_ih0 + (size_t)j * kH2);
    const float4* Wz = (const float4*)(W_ih0 + (size_t)(j + kH) * kH2);
    const float4* Wn = (const float4*)(W_ih0 + (size_t)(j + 2 * kH) * kH2);
    float ar = 0.f, az = 0.f, an = 0.f;
#pragma unroll
    for (int i = 0; i < 8; i++) {
      const int idx = lane + i * 64;  // over 512 float4 = 2048 floats
      const float4 xv = (idx < kH4) ? embr[idx] : lc4[idx - kH4];
      ar += dot4(ntld(Wr + idx), xv);
      az += dot4(ntld(Wz + idx), xv);
      an += dot4(ntld(Wn + idx), xv);
    }
    const float4* Ur = (const float4*)(W_hh0 + (size_t)j * kH);
    const float4* Uz = (const float4*)(W_hh0 + (size_t)(j + kH) * kH);
    const float4* Un = (const float4*)(W_hh0 + (size_t)(j + 2 * kH) * kH);
    const float4* h4 = (const float4*)lh;  // h_prev0 = last_hidden[0]
    float br = 0.f, bz = 0.f, bn = 0.f;
#pragma unroll
    for (int i = 0; i < 4; i++) {
      const int idx = lane + i * 64;  // over 256 float4 = 1024 floats
      const float4 hv = h4[idx];
      br += dot4(ntld(Ur + idx), hv);
      bz += dot4(ntld(Uz + idx), hv);
      bn += dot4(ntld(Un + idx), hv);
    }
    ar = wred_sum(ar); az = wred_sum(az); an = wred_sum(an);
    br = wred_sum(br); bz = wred_sum(bz); bn = wred_sum(bn);
    if (lane == 0) {
      const float ir = ar + b_ih0[j],          hr = br + b_hh0[j];
      const float iz = az + b_ih0[j + kH],     hz = bz + b_hh0[j + kH];
      const float in_ = an + b_ih0[j + 2 * kH], hn = bn + b_hh0[j + 2 * kH];
      const float r = sigmoidf_(ir + hr);
      const float z = sigmoidf_(iz + hz);
      const float n = tanhf(in_ + r * hn);
      ws[WS_H0 + j] = (1.f - z) * n + z * lh[j];
    }
  } else {
    const int row = (b - 256) * 4 + wave;  // [0, 3072)
    const float4* W  = (const float4*)(W_hh1 + (size_t)row * kH);
    const float4* h4 = (const float4*)(lh + kH);  // h_prev1
    float a = 0.f;
#pragma unroll
    for (int i = 0; i < 4; i++) {
      const int idx = lane + i * 64;
      a += dot4(ntld(W + idx), h4[idx]);
    }
    a = wred_sum(a);
    if (lane == 0) ws[WS_GH1 + row] = a + b_hh1[row];
  }
}

// K2: GRU1 -> h1 ; write hidden outputs ; zero v accumulator
__global__ void k2_gru1(const float* __restrict__ lh, const float* __restrict__ W_ih1,
                        const float* __restrict__ b_ih1, float* __restrict__ ws,
                        float* __restrict__ out) {
  const int wave = threadIdx.x >> 6, lane = threadIdx.x & 63;
  const int j = blockIdx.x * 4 + wave;
  const float4* x4 = (const float4*)(ws + WS_H0);
  const float4* Wr = (const float4*)(W_ih1 + (size_t)j * kH);
  const float4* Wz = (const float4*)(W_ih1 + (size_t)(j + kH) * kH);
  const float4* Wn = (const float4*)(W_ih1 + (size_t)(j + 2 * kH) * kH);
  float ar = 0.f, az = 0.f, an = 0.f;
#pragma unroll
  for (int i = 0; i < 4; i++) {
    const int idx = lane + i * 64;
    const float4 xv = x4[idx];
    ar += dot4(ntld(Wr + idx), xv);
    az += dot4(ntld(Wz + idx), xv);
    an += dot4(ntld(Wn + idx), xv);
  }
  ar = wred_sum(ar); az = wred_sum(az); an = wred_sum(an);
  if (lane == 0) {
    const float r = sigmoidf_(ar + b_ih1[j] + ws[WS_GH1 + j]);
    const float z = sigmoidf_(az + b_ih1[j + kH] + ws[WS_GH1 + j + kH]);
    const float n = tanhf(an + b_ih1[j + 2 * kH] + r * ws[WS_GH1 + j + 2 * kH]);
    const float h1 = (1.f - z) * n + z * lh[kH + j];
    ws[WS_H1 + j] = h1;
    out[OUT_HID + kH + j] = h1;          // hidden[1]
    out[OUT_HID + j] = ws[WS_H0 + j];    // hidden[0]
  }
  if (blockIdx.x < 4) ws[WS_V + blockIdx.x * 256 + threadIdx.x] = 0.f;  // zero v
}

// K3: fused.
//   blocks [0,64):  v = W_attn.T @ h1 partials (atomics)
//   block  64:      c = dot(b_attn, h1)
//   blocks [65, 65+12565): logits_h1[row] = W_out[row, :1024] . h1 + b_out[row]
// The tiny v/c latency hides under the 206 MB W_out half-stream.
__global__ void k3_attnv_logh1(const float* __restrict__ W_attn, const float* __restrict__ b_attn,
                               const float* __restrict__ W_out, const float* __restrict__ b_out,
                               float* __restrict__ ws) {
  __shared__ float red[4];
  const int b = blockIdx.x, t = threadIdx.x;
  const int wave = t >> 6, lane = t & 63;
  if (b >= 65) {
    const int row = (b - 65) * 4 + wave;
    if (row >= kV) return;
    const float4* W4  = (const float4*)(W_out + (size_t)row * kH2);  // first 1024 cols
    const float4* h14 = (const float4*)(ws + WS_H1);
    float a = 0.f;
#pragma unroll
    for (int i = 0; i < 4; i++) {
      const int idx = lane + i * 64;  // over 256 float4 = 1024 floats
      a += dot4(ntld(W4 + idx), h14[idx]);
    }
    a = wred_sum(a);
    if (lane == 0) ws[WS_LOGITS + row] = a + b_out[row];
    return;
  }
  if (b < 64) {
    const float4* W4 = (const float4*)W_attn;
    float4 acc = make_float4(0.f, 0.f, 0.f, 0.f);
    const int j0 = b * 16;
#pragma unroll
    for (int jj = 0; jj < 16; jj++) {
      const int j = j0 + jj;
      const float s = ws[WS_H1 + j];
      const float4 w = ntld(W4 + (size_t)j * kH4 + t);
      acc.x += s * w.x; acc.y += s * w.y; acc.z += s * w.z; acc.w += s * w.w;
    }
    atomicAdd(&ws[WS_V + 4 * t + 0], acc.x);
    atomicAdd(&ws[WS_V + 4 * t + 1], acc.y);
    atomicAdd(&ws[WS_V + 4 * t + 2], acc.z);
    atomicAdd(&ws[WS_V + 4 * t + 3], acc.w);
  } else {
    float a = 0.f;
    for (int i = t; i < kH; i += 256) a += b_attn[i] * ws[WS_H1 + i];
    const float wsum = wred_sum(a);
    if (lane == 0) red[wave] = wsum;
    __syncthreads();
    if (t == 0) ws[WS_SC + 0] = red[0] + red[1] + red[2] + red[3];
  }
}

// K4: energies[s] = dot(enc[s], v) + c   (enc loads stay cached for K6)
__global__ void k4_energies(const float* __restrict__ enc, float* __restrict__ ws) {
  const int wave = threadIdx.x >> 6, lane = threadIdx.x & 63;
  const int s = blockIdx.x * 4 + wave;
  const float4* e4 = (const float4*)(enc + (size_t)s * kH);
  const float4* v4 = (const float4*)(ws + WS_V);
  float a = 0.f;
#pragma unroll
  for (int i = 0; i < 4; i++) {
    const int idx = lane + i * 64;
    a += dot4(e4[idx], v4[idx]);
  }
  a = wred_sum(a);
  if (lane == 0) ws[WS_E + s] = a + ws[WS_SC + 0];
}

// K5: softmax over S=4096 (one block, 1024 threads); write attn out; zero ctx accumulator
__global__ void k5_softmax(float* __restrict__ ws, float* __restrict__ out) {
  __shared__ float red[16];
  const int t = threadIdx.x, lane = t & 63, wave = t >> 6;
  const float4 e = ((const float4*)(ws + WS_E))[t];
  float m = fmaxf(fmaxf(e.x, e.y), fmaxf(e.z, e.w));
  float wm = wred_max(m);
  if (lane == 0) red[wave] = wm;
  __syncthreads();
  if (wave == 0) {
    float x = (lane < 16) ? red[lane] : -INFINITY;
    x = wred_max(x);
    if (lane == 0) red[0] = x;
  }
  __syncthreads();
  m = red[0];
  __syncthreads();
  float4 ex;
  ex.x = __expf(e.x - m); ex.y = __expf(e.y - m);
  ex.z = __expf(e.z - m); ex.w = __expf(e.w - m);
  float s = ex.x + ex.y + ex.z + ex.w;
  float wsum = wred_sum(s);
  if (lane == 0) red[wave] = wsum;
  __syncthreads();
  if (wave == 0) {
    float x = (lane < 16) ? red[lane] : 0.f;
    x = wred_sum(x);
    if (lane == 0) red[0] = x;
  }
  __syncthreads();
  const float inv = 1.0f / red[0];
  float4 a4 = make_float4(ex.x * inv, ex.y * inv, ex.z * inv, ex.w * inv);
  ((float4*)(ws + WS_ATTN))[t] = a4;
  // d_out attn region is only 4B-aligned -> scalar stores
  out[OUT_ATTN + 4 * t + 0] = a4.x;
  out[OUT_ATTN + 4 * t + 1] = a4.y;
  out[OUT_ATTN + 4 * t + 2] = a4.z;
  out[OUT_ATTN + 4 * t + 3] = a4.w;
  ws[WS_CTX + t] = 0.f;  // zero context accumulator (t < 1024)
}

// K6: context = attn @ enc  (64 blocks x 64 rows each, atomic partials)
__global__ void k6_context(const float* __restrict__ enc, float* __restrict__ ws) {
  const int b = blockIdx.x, t = threadIdx.x;
  const float4* e4 = (const float4*)enc;
  float4 acc = make_float4(0.f, 0.f, 0.f, 0.f);
  const int s0 = b * 64;
  for (int ss = 0; ss < 64; ss++) {
    const int s = s0 + ss;
    const float a = ws[WS_ATTN + s];
    const float4 ev = e4[(size_t)s * kH4 + t];
    acc.x += a * ev.x; acc.y += a * ev.y; acc.z += a * ev.z; acc.w += a * ev.w;
  }
  atomicAdd(&ws[WS_CTX + 4 * t + 0], acc.x);
  atomicAdd(&ws[WS_CTX + 4 * t + 1], acc.y);
  atomicAdd(&ws[WS_CTX + 4 * t + 2], acc.z);
  atomicAdd(&ws[WS_CTX + 4 * t + 3], acc.w);
}

// K7: logits[row] += W_out[row, 1024:] . ctx   (the other 206 MB half-stream)
__global__ void k7_logits_ctx(const float* __restrict__ W_out, float* __restrict__ ws) {
  const int wave = threadIdx.x >> 6, lane = threadIdx.x & 63;
  const int row = blockIdx.x * 4 + wave;
  if (row >= kV) return;
  const float4* W4 = (const float4*)(W_out + (size_t)row * kH2 + kH);  // cols [1024,2048)
  const float4* c4 = (const float4*)(ws + WS_CTX);
  float a = 0.f;
#pragma unroll
  for (int i = 0; i < 4; i++) {
    const int idx = lane + i * 64;
    a += dot4(ntld(W4 + idx), c4[idx]);
  }
  a = wred_sum(a);
  if (lane == 0) ws[WS_LOGITS + row] += a;  // unique row owner
}

// K8m: single block computes global max and log-sum-exp over 50257 logits (L2-hot, 200 KB)
__global__ void k8m_maxlse(float* __restrict__ ws) {
  __shared__ float red[16];
  const int t = threadIdx.x, lane = t & 63, wave = t >> 6;
  float m = -INFINITY;
  for (int g = t; g < kV; g += 1024) m = fmaxf(m, ws[WS_LOGITS + g]);
  m = wred_max(m);
  if (lane == 0) red[wave] = m;
  __syncthreads();
  if (wave == 0) {
    float x = (lane < 16) ? red[lane] : -INFINITY;
    x = wred_max(x);
    if (lane == 0) red[0] = x;
  }
  __syncthreads();
  const float gm = red[0];
  __syncthreads();
  float s = 0.f;
  for (int g = t; g < kV; g += 1024) s += __expf(ws[WS_LOGITS + g] - gm);
  s = wred_sum(s);
  if (lane == 0) red[wave] = s;
  __syncthreads();
  if (t == 0) {
    float gs = 0.f;
#pragma unroll
    for (int i = 0; i < 16; i++) gs += red[i];
    ws[WS_SC + 1] = gm;
    ws[WS_SC + 2] = logf(gs);
  }
}

// K8c: final writes — log-softmax output + context copy
__global__ void k8c_output(const float* __restrict__ ws, float* __restrict__ out) {
  const int g = blockIdx.x * 256 + threadIdx.x;
  const float shift = ws[WS_SC + 1] + ws[WS_SC + 2];
  if (g < kV) out[OUT_LOGITS + g] = ws[WS_LOGITS + g] - shift;
  if (g < kH) out[OUT_CTX + g] = ws[WS_CTX + g];
}

extern "C" void kernel_launch(void* const* d_in, const int* in_sizes, int n_in,
                              void* d_out, int out_size, void* d_ws, size_t ws_size,
                              hipStream_t stream) {
  const int*   wi     = (const int*)d_in[0];
  const float* lc     = (const float*)d_in[1];
  const float* lh     = (const float*)d_in[2];
  const float* enc    = (const float*)d_in[3];
  const float* emb    = (const float*)d_in[4];
  const float* W_ih0  = (const float*)d_in[5];
  const float* W_hh0  = (const float*)d_in[6];
  const float* b_ih0  = (const float*)d_in[7];
  const float* b_hh0  = (const float*)d_in[8];
  const float* W_ih1  = (const float*)d_in[9];
  const float* W_hh1  = (const float*)d_in[10];
  const float* b_ih1  = (const float*)d_in[11];
  const float* b_hh1  = (const float*)d_in[12];
  const float* W_attn = (const float*)d_in[13];
  const float* b_attn = (const float*)d_in[14];
  const float* W_out  = (const float*)d_in[15];
  const float* b_out  = (const float*)d_in[16];
  float* out = (float*)d_out;
  float* ws  = (float*)d_ws;

  constexpr int kLogitBlocks = (kV + 3) / 4;  // 12565

  k1_gru0_gh1<<<1024, 256, 0, stream>>>(wi, lc, lh, emb, W_ih0, W_hh0, b_ih0, b_hh0,
                                        W_hh1, b_hh1, ws);
  k2_gru1<<<256, 256, 0, stream>>>(lh, W_ih1, b_ih1, ws, out);
  k3_attnv_logh1<<<65 + kLogitBlocks, 256, 0, stream>>>(W_attn, b_attn, W_out, b_out, ws);
  k4_energies<<<1024, 256, 0, stream>>>(enc, ws);
  k5_softmax<<<1, 1024, 0, stream>>>(ws, out);
  k6_context<<<64, 256, 0, stream>>>(enc, ws);
  k7_logits_ctx<<<kLogitBlocks, 256, 0, stream>>>(W_out, ws);
  k8m_maxlse<<<1, 1024, 0, stream>>>(ws);
  k8c_output<<<(kV + 255) / 256, 256, 0, stream>>>(ws, out);
}